// Round 18
// baseline (241.439 us; speedup 1.0000x reference)
//
#include <hip/hip_runtime.h>
#include <hip/hip_bf16.h>
#include <stdint.h>

using bf16 = __hip_bfloat16;
using bf16x8 = __attribute__((ext_vector_type(8))) short;
using f32x4  = __attribute__((ext_vector_type(4))) float;
using short4v = __attribute__((ext_vector_type(4))) short;

#define EPSF 1e-6f
#define LOG2E 1.44269504088896f

__device__ __forceinline__ unsigned short f2bu(float x) {
  union { bf16 h; unsigned short u; } cvt;
  cvt.h = __float2bfloat16(x);
  return cvt.u;
}

typedef __attribute__((address_space(3))) void as3_void;
typedef const __attribute__((address_space(1))) void as1_void;

__device__ __forceinline__ void gload_lds16(const void* g, void* l) {
  as1_void* gp = (as1_void*)(uintptr_t)g;
  as3_void* lp = (as3_void*)(uint32_t)(uintptr_t)l;  // generic LDS ptr low 32 bits = LDS offset
  __builtin_amdgcn_global_load_lds(gp, lp, 16, 0, 0);
}

// ======== preamble: rope tables + ada stage-1 + all 5 weight transposes, one launch ====
__global__ void __launch_bounds__(256) preamble(const float* __restrict__ qkvw,
                                                const float* __restrict__ projw,
                                                const float* __restrict__ w1,
                                                const float* __restrict__ w3,
                                                const float* __restrict__ w2,
                                                bf16* __restrict__ qkvwt,
                                                bf16* __restrict__ projwt,
                                                bf16* __restrict__ w1t,
                                                bf16* __restrict__ w3t,
                                                bf16* __restrict__ w2t,
                                                const float* __restrict__ cc,
                                                const float* __restrict__ adaw,
                                                float* __restrict__ part,
                                                float* __restrict__ cosT,
                                                float* __restrict__ sinT) {
  __shared__ float tile[32][33];
  __shared__ float sc[256];
  __shared__ float red[1024];
  int id = blockIdx.x;
  const int t = threadIdx.x;
  if (id < 12416) {
    const float* src; bf16* dst; int R, Cc, ldd, nbx;
    if (id < 3072)      { src = qkvw;  dst = qkvwt;  R = 1024; Cc = 3072; ldd = 1024; nbx = 96; }
    else if ((id -= 3072) < 1024) { src = projw; dst = projwt; R = 1024; Cc = 1024; ldd = 1024; nbx = 32; }
    else if ((id -= 1024) < 2752) { src = w1;    dst = w1t;    R = 1024; Cc = 2730; ldd = 1024; nbx = 86; }
    else if ((id -= 2752) < 2752) { src = w3;    dst = w3t;    R = 1024; Cc = 2730; ldd = 1024; nbx = 86; }
    else                { id -= 2752; src = w2;    dst = w2t;    R = 2730; Cc = 1024; ldd = 2816; nbx = 32; }
    const int bx = id % nbx, by = id / nbx;
    const int tx = t & 31, ty = t >> 5;
    const int ct = bx * 32, rt = by * 32;
#pragma unroll
    for (int kk = 0; kk < 4; ++kk) {
      const int r = rt + ty + kk * 8;
      float v = 0.f;
      if (r < R && (ct + tx) < Cc) v = src[(size_t)r * Cc + ct + tx];
      tile[ty + kk * 8][tx] = v;
    }
    __syncthreads();
#pragma unroll
    for (int kk = 0; kk < 4; ++kk) {
      const int c = ct + ty + kk * 8;
      const int r = rt + tx;
      if (c < Cc && r < ldd) dst[(size_t)c * ldd + r] = __float2bfloat16(tile[tx][ty + kk * 8]);
    }
  } else if ((id -= 12416) < 768) {
    const int cb = id % 48, ks = id / 48;
    const int k0 = ks * 64;
    {
      const int b = t >> 6, kk = t & 63;
      const float v = cc[b * 1024 + k0 + kk];
      sc[t] = v / (1.f + __expf(-v));
    }
    __syncthreads();
    const int colL = t & 127, kh = t >> 7;
    const int col = cb * 128 + colL;
    float a0 = 0.f, a1 = 0.f, a2 = 0.f, a3 = 0.f;
    const float* ap = adaw + (size_t)(k0 + kh * 32) * 6144 + col;
#pragma unroll
    for (int k = 0; k < 32; ++k) {
      const float awv = ap[(size_t)k * 6144];
      const int kk = kh * 32 + k;
      a0 += sc[kk] * awv; a1 += sc[64 + kk] * awv;
      a2 += sc[128 + kk] * awv; a3 += sc[192 + kk] * awv;
    }
    red[kh * 512 + 0 * 128 + colL] = a0;
    red[kh * 512 + 1 * 128 + colL] = a1;
    red[kh * 512 + 2 * 128 + colL] = a2;
    red[kh * 512 + 3 * 128 + colL] = a3;
    __syncthreads();
    if (kh == 0) {
#pragma unroll
      for (int b = 0; b < 4; ++b) {
        const float s = red[b * 128 + colL] + red[512 + b * 128 + colL];
        part[(size_t)(ks * 4 + b) * 6144 + col] = s;
      }
    }
  } else {
    id -= 768;
    const int i = id * 256 + t;
    const int n = i >> 5, fi = i & 31;
    const float invf = powf(10000.f, -(float)fi * (1.f / 32.f));
    const float ang = (float)n * invf;
    cosT[i] = cosf(ang);
    sinT[i] = sinf(ang);
  }
}

// ---------------- ada stage 2: mods[b][col] = sum_ks partial + bias ----------------
__global__ void __launch_bounds__(256) ada_reduce(const float* __restrict__ part,
                                                  const float* __restrict__ adab,
                                                  float* __restrict__ mods) {
  const int i = blockIdx.x * 256 + threadIdx.x;   // 24576 = 4*6144
  const int b = i / 6144, col = i % 6144;
  float s = adab[col];
#pragma unroll
  for (int ks = 0; ks < 16; ++ks) s += part[(size_t)(ks * 4 + b) * 6144 + col];
  mods[b * 6144 + col] = s;
}

// ---------------- y = rmsnorm(x,w)*(1+sc)+sh  -> bf16 ----------------
__global__ void __launch_bounds__(256) norm_mod(const float* __restrict__ X,
                                                const float* __restrict__ wgt,
                                                const float* __restrict__ mods,
                                                int sh_off, int sc_off,
                                                bf16* __restrict__ Y) {
  __shared__ float red[4];
  const int row = blockIdx.x, t = threadIdx.x, l = t & 63, wv = t >> 6;
  const float4 xv = ((const float4*)(X + (size_t)row * 1024))[t];
  float ss = xv.x * xv.x + xv.y * xv.y + xv.z * xv.z + xv.w * xv.w;
#pragma unroll
  for (int off = 1; off < 64; off <<= 1) ss += __shfl_xor(ss, off);
  if (l == 0) red[wv] = ss;
  __syncthreads();
  ss = (red[0] + red[1]) + (red[2] + red[3]);
  const float rs = rsqrtf(ss * (1.f / 1024.f) + EPSF);
  const int b = row >> 10;
  const float* mb = mods + b * 6144;
  const int c0 = t * 4;
  float vals[4] = {xv.x, xv.y, xv.z, xv.w};
  short4v yv;
#pragma unroll
  for (int j = 0; j < 4; j++) {
    const int cc = c0 + j;
    const float y = vals[j] * rs * wgt[cc] * (1.f + mb[sc_off + cc]) + mb[sh_off + cc];
    yv[j] = (short)f2bu(y);
  }
  *(short4v*)(Y + (size_t)row * 1024 + c0) = yv;
}

// ======== gemm_p: C = A[M,K]@Bt[N,K]^T, 128x64 tile, 4 waves, RING-2 (R18) =============
// Ring-2 at (256,3): LDS 2x12KB = 24KB -> HW occupancy 5 blocks/CU (VGPR-capped at
// 2048/100 = 20 waves). R13's spill came from (256,4) allocator pressure, NOT ring-2;
// (256,3) is proven no-spill at VGPR ~100. Counting: prologue stage(0); per-iter
// stage(kt+1) -> outstanding 2L, vmcnt(L) completes tile kt; end barrier = WAR.
template <int EPI>
__global__ void __launch_bounds__(256, 3) gemm_p(const bf16* __restrict__ A, int lda,
                                                 const bf16* __restrict__ Bt, int ldb,
                                                 int K, int ldc,
                                                 float* __restrict__ outf,
                                                 const float* __restrict__ resid,
                                                 const float* __restrict__ gate,
                                                 const float* __restrict__ bias) {
  constexpr int BUFSZ = 12288;
  __shared__ char smB[2 * BUFSZ];
  const int t = threadIdx.x, l = t & 63, w = t >> 6;
  const int g = l >> 4, cl = l & 15;
  const int cpx = gridDim.x >> 3;
  const int wg = blockIdx.x;
  const int swz0 = (wg & 7) * cpx + (wg >> 3);
  const int m0 = (swz0 & 31) * 128, n0 = (swz0 >> 5) * 64;   // m-major (M=4096 fixed)
  f32x4 acc[2][4] = {};
  const int NK = K >> 5;
  const int srow = t >> 2;
  const int scol = (((t & 3) ^ ((t >> 3) & 3))) * 8;
  const int rsw = (cl >> 1) & 3;

  auto stage = [&](int kt, int buf) {
    char* dst = smB + buf * BUFSZ;
    const int kk = kt * 32 + scol;
    gload_lds16(A + (size_t)(m0 + srow) * lda + kk,      dst + t * 16);
    gload_lds16(A + (size_t)(m0 + 64 + srow) * lda + kk, dst + 4096 + t * 16);
    gload_lds16(Bt + (size_t)(n0 + srow) * ldb + kk,     dst + 8192 + t * 16);
  };

  stage(0, 0);
  for (int kt = 0; kt < NK; ++kt) {
    if (kt + 1 < NK) {
      stage(kt + 1, (kt + 1) & 1);
      asm volatile("s_waitcnt vmcnt(3)" ::: "memory");
    } else {
      asm volatile("s_waitcnt vmcnt(0)" ::: "memory");
    }
    __builtin_amdgcn_s_barrier();
    __builtin_amdgcn_sched_barrier(0);
    const bf16* Ab = (const bf16*)(smB + (kt & 1) * BUFSZ);
    const bf16* Bb = (const bf16*)(smB + (kt & 1) * BUFSZ + 8192);
    bf16x8 af[2], bfr[4];
#pragma unroll
    for (int i = 0; i < 2; i++)
      af[i] = *(const bf16x8*)&Ab[(w * 32 + i * 16 + cl) * 32 + ((g ^ rsw) << 3)];
#pragma unroll
    for (int i = 0; i < 4; i++)
      bfr[i] = *(const bf16x8*)&Bb[(i * 16 + cl) * 32 + ((g ^ rsw) << 3)];
    __builtin_amdgcn_s_setprio(1);
#pragma unroll
    for (int mi = 0; mi < 2; mi++)
#pragma unroll
      for (int ni = 0; ni < 4; ni++)
        acc[mi][ni] = __builtin_amdgcn_mfma_f32_16x16x32_bf16(af[mi], bfr[ni], acc[mi][ni], 0, 0, 0);
    __builtin_amdgcn_s_setprio(0);
    __builtin_amdgcn_s_barrier();
    __builtin_amdgcn_sched_barrier(0);
  }
#pragma unroll
  for (int mi = 0; mi < 2; mi++) {
#pragma unroll
    for (int ni = 0; ni < 4; ni++) {
      const int c = n0 + ni * 16 + cl;
#pragma unroll
      for (int j = 0; j < 4; j++) {
        const int r = m0 + w * 32 + mi * 16 + g * 4 + j;
        const float v = acc[mi][ni][j];
        if constexpr (EPI == 1) {
          const int b = r >> 10;
          outf[(size_t)r * ldc + c] = resid[(size_t)r * ldc + c] + gate[b * 6144 + c] * (v + bias[c]);
        } else if constexpr (EPI == 4) {
          const int b = r >> 10;
          outf[(size_t)r * ldc + c] = resid[(size_t)r * ldc + c] + gate[b * 6144 + c] * v;
        }
      }
    }
  }
}

// ======== gemm_qkv: qkv GEMM + fused rmsnorm/RoPE/scatter, RING-2 (R18) ================
// LDS 2x16KB = 32KB -> 5 blocks/CU (VGPR ~100 -> 20-wave cap). Rope scratch = exactly
// the 32KB (cosS 16K + sinS 16K). Q pre-scaled 0.125*log2e for exp2-domain softmax.
__global__ void __launch_bounds__(256, 3) gemm_qkv(const bf16* __restrict__ A, int lda,
                                                   const bf16* __restrict__ Bt, int ldb,
                                                   const float* __restrict__ cosT,
                                                   const float* __restrict__ sinT,
                                                   const float* __restrict__ qnw,
                                                   const float* __restrict__ knw,
                                                   bf16* __restrict__ Qo,
                                                   bf16* __restrict__ Ko,
                                                   bf16* __restrict__ vbt) {
  constexpr int BUFSZ = 16384;
  __shared__ char smB[2 * BUFSZ];
  const int t = threadIdx.x, l = t & 63, w = t >> 6;
  const int g = l >> 4, cl = l & 15;
  const int cpx = gridDim.x >> 3;
  const int wg = blockIdx.x;
  const int swz0 = (wg & 7) * cpx + (wg >> 3);
  const int m0 = (swz0 & 31) * 128, n0 = (swz0 >> 5) * 128;
  const int wm = w >> 1, wn = w & 1;
  f32x4 acc[4][4] = {};
  const int srow = t >> 2;
  const int scol = (((t & 3) ^ ((t >> 3) & 3))) * 8;
  const int rsw = (cl >> 1) & 3;

  auto stage = [&](int kt, int buf) {
    char* dst = smB + buf * BUFSZ;
    const int kk = kt * 32 + scol;
    gload_lds16(A + (size_t)(m0 + srow) * lda + kk,       dst + t * 16);
    gload_lds16(A + (size_t)(m0 + 64 + srow) * lda + kk,  dst + 4096 + t * 16);
    gload_lds16(Bt + (size_t)(n0 + srow) * ldb + kk,      dst + 8192 + t * 16);
    gload_lds16(Bt + (size_t)(n0 + 64 + srow) * ldb + kk, dst + 12288 + t * 16);
  };

  stage(0, 0);
  for (int kt = 0; kt < 32; ++kt) {
    if (kt + 1 < 32) {
      stage(kt + 1, (kt + 1) & 1);
      asm volatile("s_waitcnt vmcnt(4)" ::: "memory");
    } else {
      asm volatile("s_waitcnt vmcnt(0)" ::: "memory");
    }
    __builtin_amdgcn_s_barrier();
    __builtin_amdgcn_sched_barrier(0);
    const bf16* Ab = (const bf16*)(smB + (kt & 1) * BUFSZ);
    const bf16* Bb = (const bf16*)(smB + (kt & 1) * BUFSZ + 8192);
    bf16x8 af[4], bfr[4];
#pragma unroll
    for (int i = 0; i < 4; i++)
      af[i] = *(const bf16x8*)&Ab[(wm * 64 + i * 16 + cl) * 32 + ((g ^ rsw) << 3)];
#pragma unroll
    for (int i = 0; i < 4; i++)
      bfr[i] = *(const bf16x8*)&Bb[(wn * 64 + i * 16 + cl) * 32 + ((g ^ rsw) << 3)];
    __builtin_amdgcn_s_setprio(1);
#pragma unroll
    for (int mi = 0; mi < 4; mi++)
#pragma unroll
      for (int ni = 0; ni < 4; ni++)
        acc[mi][ni] = __builtin_amdgcn_mfma_f32_16x16x32_bf16(af[mi], bfr[ni], acc[mi][ni], 0, 0, 0);
    __builtin_amdgcn_s_setprio(0);
    __builtin_amdgcn_s_barrier();
    __builtin_amdgcn_sched_barrier(0);
  }

  // ---- stage rope tables for this token block into LDS (smB free after final barrier) --
  float* cosS = (float*)smB;            // [128][32]
  float* sinS = (float*)(smB + 16384);  // [128][32]
  const int nb0 = m0 & 1023;
  for (int i = t; i < 4096; i += 256) {
    cosS[i] = cosT[(nb0 + (i >> 5)) * 32 + (i & 31)];
    sinS[i] = sinT[(nb0 + (i >> 5)) * 32 + (i & 31)];
  }
  __syncthreads();

  const int hb = n0 + wn * 64;            // this wave's 64-col head chunk
  const int type = hb >> 10;              // 0 Q, 1 K, 2 V
  const int h = (hb & 1023) >> 6;
  const int b = m0 >> 10;
  const int bh = b * 16 + h;

  if (type == 2) {
#pragma unroll
    for (int mi = 0; mi < 4; mi++) {
      const int r0 = m0 + wm * 64 + mi * 16 + g * 4;
      const int nn0 = r0 & 1023;
#pragma unroll
      for (int ni = 0; ni < 4; ni++) {
        const int d = ni * 16 + cl;
        short4v pv;
#pragma unroll
        for (int j = 0; j < 4; j++) pv[j] = (short)f2bu(acc[mi][ni][j]);
        *(short4v*)(vbt + (size_t)bh * 65536 + (size_t)d * 1024 + nn0) = pv;
      }
    }
  } else {
    bf16* dst = (type == 0) ? Qo : Ko;
    const float* nwp = (type == 0) ? qnw : knw;
    const float scale = (type == 0) ? 0.125f * LOG2E : 1.f;
    float wv[4];
#pragma unroll
    for (int ni = 0; ni < 4; ni++) wv[ni] = nwp[ni * 16 + cl];
#pragma unroll
    for (int mi = 0; mi < 4; mi++) {
#pragma unroll
      for (int j = 0; j < 4; j++) {
        float ssq = 0.f;
#pragma unroll
        for (int ni = 0; ni < 4; ni++) ssq += acc[mi][ni][j] * acc[mi][ni][j];
        ssq += __shfl_xor(ssq, 1);
        ssq += __shfl_xor(ssq, 2);
        ssq += __shfl_xor(ssq, 4);
        ssq += __shfl_xor(ssq, 8);
        const float rsn = rsqrtf(ssq * (1.f / 64.f) + EPSF);
        const int r = m0 + wm * 64 + mi * 16 + g * 4 + j;
        const int nn = r & 1023, rr = r - m0;
        float vn[4];
#pragma unroll
        for (int ni = 0; ni < 4; ni++) vn[ni] = acc[mi][ni][j] * rsn * wv[ni];
        const float cs0 = cosS[rr * 32 + cl],      sn0 = sinS[rr * 32 + cl];
        const float cs1 = cosS[rr * 32 + 16 + cl], sn1 = sinS[rr * 32 + 16 + cl];
        const float o0 = (vn[0] * cs0 - vn[2] * sn0) * scale;
        const float o1 = (vn[1] * cs1 - vn[3] * sn1) * scale;
        const float o2 = (vn[2] * cs0 + vn[0] * sn0) * scale;
        const float o3 = (vn[3] * cs1 + vn[1] * sn1) * scale;
        const size_t base = ((size_t)bh * 1024 + nn) * 64;
        dst[base + cl] = __float2bfloat16(o0);
        dst[base + 16 + cl] = __float2bfloat16(o1);
        dst[base + 32 + cl] = __float2bfloat16(o2);
        dst[base + 48 + cl] = __float2bfloat16(o3);
      }
    }
  }
}

// ======== gemm_dual: fused h = silu(A@W1^T)*(A@W3^T), 128x128, dual accumulators =======
// RING-2 at (256,2) (R14 proven): 48KB LDS, VGPR ~100 no spill. m-major block order.
__global__ void __launch_bounds__(256, 2) gemm_dual(const bf16* __restrict__ A, int lda,
                                                    const bf16* __restrict__ B1t,
                                                    const bf16* __restrict__ B3t, int ldb,
                                                    int K, int Nreal, int ldc,
                                                    bf16* __restrict__ outb) {
  constexpr int BUFSZ = 24576;
  __shared__ char smB[2 * BUFSZ];
  const int t = threadIdx.x, l = t & 63, w = t >> 6;
  const int g = l >> 4, cl = l & 15;
  const int cpx = gridDim.x >> 3;
  const int wg = blockIdx.x;
  const int swz0 = (wg & 7) * cpx + (wg >> 3);
  const int m0 = (swz0 & 31) * 128, n0 = (swz0 >> 5) * 128;   // m-major (M=4096 fixed)
  const int wm = w >> 1, wn = w & 1;
  f32x4 acc1[4][4] = {}, acc3[4][4] = {};
  const int NK = K >> 5;
  const int srow = t >> 2;
  const int scol = (((t & 3) ^ ((t >> 3) & 3))) * 8;
  const int rsw = (cl >> 1) & 3;

  auto stage = [&](int kt, int buf) {
    char* dst = smB + buf * BUFSZ;
    const int kk = kt * 32 + scol;
    gload_lds16(A   + (size_t)(m0 + srow) * lda + kk,      dst + t * 16);
    gload_lds16(A   + (size_t)(m0 + 64 + srow) * lda + kk, dst + 4096 + t * 16);
    gload_lds16(B1t + (size_t)(n0 + srow) * ldb + kk,      dst + 8192 + t * 16);
    gload_lds16(B1t + (size_t)(n0 + 64 + srow) * ldb + kk, dst + 12288 + t * 16);
    gload_lds16(B3t + (size_t)(n0 + srow) * ldb + kk,      dst + 16384 + t * 16);
    gload_lds16(B3t + (size_t)(n0 + 64 + srow) * ldb + kk, dst + 20480 + t * 16);
  };

  stage(0, 0);
  for (int kt = 0; kt < NK; ++kt) {
    if (kt + 1 < NK) {
      stage(kt + 1, (kt + 1) & 1);
      asm volatile("s_waitcnt vmcnt(6)" ::: "memory");
    } else {
      asm volatile("s_waitcnt vmcnt(0)" ::: "memory");
    }
    __builtin_amdgcn_s_barrier();
    __builtin_amdgcn_sched_barrier(0);
    const bf16* Ab  = (const bf16*)(smB + (kt & 1) * BUFSZ);
    const bf16* B1b = (const bf16*)(smB + (kt & 1) * BUFSZ + 8192);
    const bf16* B3b = (const bf16*)(smB + (kt & 1) * BUFSZ + 16384);
    bf16x8 af[4], b1r[4], b3r[4];
#pragma unroll
    for (int i = 0; i < 4; i++)
      af[i] = *(const bf16x8*)&Ab[(wm * 64 + i * 16 + cl) * 32 + ((g ^ rsw) << 3)];
#pragma unroll
    for (int i = 0; i < 4; i++) {
      b1r[i] = *(const bf16x8*)&B1b[(wn * 64 + i * 16 + cl) * 32 + ((g ^ rsw) << 3)];
      b3r[i] = *(const bf16x8*)&B3b[(wn * 64 + i * 16 + cl) * 32 + ((g ^ rsw) << 3)];
    }
    __builtin_amdgcn_s_setprio(1);
#pragma unroll
    for (int mi = 0; mi < 4; mi++)
#pragma unroll
      for (int ni = 0; ni < 4; ni++) {
        acc1[mi][ni] = __builtin_amdgcn_mfma_f32_16x16x32_bf16(af[mi], b1r[ni], acc1[mi][ni], 0, 0, 0);
        acc3[mi][ni] = __builtin_amdgcn_mfma_f32_16x16x32_bf16(af[mi], b3r[ni], acc3[mi][ni], 0, 0, 0);
      }
    __builtin_amdgcn_s_setprio(0);
    __builtin_amdgcn_s_barrier();
    __builtin_amdgcn_sched_barrier(0);
  }
#pragma unroll
  for (int mi = 0; mi < 4; mi++) {
#pragma unroll
    for (int ni = 0; ni < 4; ni++) {
      const int c = n0 + wn * 64 + ni * 16 + cl;
#pragma unroll
      for (int j = 0; j < 4; j++) {
        const int r = m0 + wm * 64 + mi * 16 + g * 4 + j;
        if (c < Nreal) {
          const float hv = acc1[mi][ni][j];
          const float sl = hv / (1.f + __expf(-hv));
          outb[(size_t)r * ldc + c] = __float2bfloat16(sl * acc3[mi][ni][j]);
        } else {
          outb[(size_t)r * ldc + c] = __float2bfloat16(0.f);
        }
      }
    }
  }
}

// ---------------- flash attention v7: exp2-domain softmax + defer-max (T13) ------------
__global__ void __launch_bounds__(512) attn_fwd(const bf16* __restrict__ Qb,
                                                const bf16* __restrict__ Kb,
                                                const bf16* __restrict__ Vb,
                                                bf16* __restrict__ Ob) {
  __shared__ char KsB[2 * 8192];              // [buf][64 kv][8 slots of 16B], xor-swizzled
  __shared__ char VsB[2 * 8192];              // [buf][64 d][8 kv-slots of 16B], xor-swizzled
  __shared__ unsigned short Ps[8 * 16 * 64];  // per-wave P tile [16 q][8 kv-chunks], xor-swizzled
  const int t = threadIdx.x, l = t & 63, w = t >> 6;
  const int g = l >> 4, cl = l & 15;
  const int wg = blockIdx.x;
  const int bh = wg & 63;
  const int q0 = (wg >> 6) * 128;
  const bf16* Qg = Qb + (size_t)bh * 65536;
  const bf16* Kg = Kb + (size_t)bh * 65536;
  const bf16* Vg = Vb + (size_t)bh * 65536;   // [d][n] layout
  const int qrow = q0 + w * 16 + cl;
  const bf16x8 aq0 = *(const bf16x8*)(Qg + (size_t)qrow * 64 + g * 8);
  const bf16x8 aq1 = *(const bf16x8*)(Qg + (size_t)qrow * 64 + 32 + g * 8);
  float mreg = -1e30f, lreg = 0.f;
  f32x4 o[4] = {};
  const int kr_l = t >> 3;                    // K: kv-row / V: d-row (0..63)
  const int ku = (t & 7) ^ ((t >> 3) & 7);    // source chunk for phys chunk t&7
  unsigned short* Pw = Ps + w * 1024;
  const int sxor = cl & 7;

  auto stageKV = [&](int kvt, int buf) {
    const int kv0 = kvt * 64;
    gload_lds16(Kg + (size_t)(kv0 + kr_l) * 64 + ku * 8, KsB + buf * 8192 + w * 1024);
    gload_lds16(Vg + (size_t)kr_l * 1024 + kv0 + ku * 8, VsB + buf * 8192 + w * 1024);
  };

  stageKV(0, 0);
  for (int kvt = 0; kvt < 16; ++kvt) {
    const int cb = kvt & 1;
    if (kvt + 1 < 16) {
      stageKV(kvt + 1, cb ^ 1);
      asm volatile("s_waitcnt vmcnt(2)" ::: "memory");
    } else {
      asm volatile("s_waitcnt vmcnt(0)" ::: "memory");
    }
    __builtin_amdgcn_s_barrier();
    __builtin_amdgcn_sched_barrier(0);
    const char* Kt = KsB + cb * 8192;
    const char* Vt = VsB + cb * 8192;
    f32x4 s[4] = {};
#pragma unroll
    for (int ch = 0; ch < 4; ch++) {
      const int rb = (16 * ch + cl) << 7;
      const bf16x8 bk0 = *(const bf16x8*)(Kt + rb + ((g ^ sxor) << 4));
      s[ch] = __builtin_amdgcn_mfma_f32_16x16x32_bf16(bk0, aq0, s[ch], 0, 0, 0);
      const bf16x8 bk1 = *(const bf16x8*)(Kt + rb + (((4 + g) ^ sxor) << 4));
      s[ch] = __builtin_amdgcn_mfma_f32_16x16x32_bf16(bk1, aq1, s[ch], 0, 0, 0);
    }
    float pm = fmaxf(fmaxf(fmaxf(s[0][0], s[0][1]), fmaxf(s[0][2], s[0][3])),
                     fmaxf(fmaxf(s[1][0], s[1][1]), fmaxf(s[1][2], s[1][3])));
    pm = fmaxf(pm, fmaxf(fmaxf(fmaxf(s[2][0], s[2][1]), fmaxf(s[2][2], s[2][3])),
                         fmaxf(fmaxf(s[3][0], s[3][1]), fmaxf(s[3][2], s[3][3]))));
    pm = fmaxf(pm, __shfl_xor(pm, 16));
    pm = fmaxf(pm, __shfl_xor(pm, 32));
    if (!__all(pm - mreg <= 8.f)) {           // defer-max: rescale only on real growth
      const float nm = fmaxf(mreg, pm);
      const float al = exp2f(mreg - nm);
      mreg = nm;
      lreg *= al;
#pragma unroll
      for (int dc = 0; dc < 4; dc++) {
        o[dc][0] *= al; o[dc][1] *= al; o[dc][2] *= al; o[dc][3] *= al;
      }
    }
    float rs = 0.f;
#pragma unroll
    for (int ch = 0; ch < 4; ch++) {
      const float p0 = exp2f(s[ch][0] - mreg);
      const float p1 = exp2f(s[ch][1] - mreg);
      const float p2 = exp2f(s[ch][2] - mreg);
      const float p3 = exp2f(s[ch][3] - mreg);
      rs += (p0 + p1) + (p2 + p3);
      short4v pk;
      pk[0] = (short)f2bu(p0); pk[1] = (short)f2bu(p1);
      pk[2] = (short)f2bu(p2); pk[3] = (short)f2bu(p3);
      const int phys = (2 * ch + (g >> 1)) ^ sxor;
      *(short4v*)&Pw[cl * 64 + phys * 8 + 4 * (g & 1)] = pk;
    }
    rs += __shfl_xor(rs, 16);
    rs += __shfl_xor(rs, 32);
    lreg += rs;
    const bf16x8 pa0 = *(const bf16x8*)&Pw[cl * 64 + ((g ^ sxor) << 3)];
    const bf16x8 pa1 = *(const bf16x8*)&Pw[cl * 64 + (((4 + g) ^ sxor) << 3)];
#pragma unroll
    for (int dc = 0; dc < 4; dc++) {
      const int vr = (16 * dc + cl) << 7;
      const bf16x8 bv0 = *(const bf16x8*)(Vt + vr + ((g ^ sxor) << 4));
      o[dc] = __builtin_amdgcn_mfma_f32_16x16x32_bf16(bv0, pa0, o[dc], 0, 0, 0);
      const bf16x8 bv1 = *(const bf16x8*)(Vt + vr + (((4 + g) ^ sxor) << 4));
      o[dc] = __builtin_amdgcn_mfma_f32_16x16x32_bf16(bv1, pa1, o[dc], 0, 0, 0);
    }
    __builtin_amdgcn_s_barrier();   // reads of buf cb done before next DMA into it
  }
  const int b = bh >> 4, h = bh & 15;
  const float inv = 1.f / lreg;
  const int q = q0 + w * 16 + cl;
  const size_t base = ((size_t)(b * 1024 + q) * 16 + h) * 64;
#pragma unroll
  for (int dc = 0; dc < 4; dc++) {
    short4v ov;
    ov[0] = (short)f2bu(o[dc][0] * inv);
    ov[1] = (short)f2bu(o[dc][1] * inv);
    ov[2] = (short)f2bu(o[dc][2] * inv);
    ov[3] = (short)f2bu(o[dc][3] * inv);
    *(short4v*)(Ob + base + 16 * dc + 4 * g) = ov;
  }
}

// ---------------- launch ----------------
extern "C" void kernel_launch(void* const* d_in, const int* in_sizes, int n_in,
                              void* d_out, int out_size, void* d_ws, size_t ws_size,
                              hipStream_t stream) {
  const float* x     = (const float*)d_in[0];
  const float* c     = (const float*)d_in[1];
  const float* n1w   = (const float*)d_in[2];
  const float* n2w   = (const float*)d_in[3];
  const float* qkvw  = (const float*)d_in[4];
  const float* projw = (const float*)d_in[5];
  const float* projb = (const float*)d_in[6];
  const float* qnw   = (const float*)d_in[7];
  const float* knw   = (const float*)d_in[8];
  const float* w1    = (const float*)d_in[9];
  const float* w2    = (const float*)d_in[10];
  const float* w3    = (const float*)d_in[11];
  const float* adaw  = (const float*)d_in[12];
  const float* adab  = (const float*)d_in[13];
  float* outp = (float*)d_out;
  char* ws = (char*)d_ws;
  if (ws_size < 93159424u) return;

  float* ropeC = (float*)(ws + 0);          // 131072
  float* ropeS = (float*)(ws + 131072);     // 131072
  float* mods  = (float*)(ws + 262144);     // 98304
  bf16* xmod   = (bf16*)(ws + 360448);      // 8388608
  bf16* qkvwt  = (bf16*)(ws + 8749056);     // 6291456  [3072][1024]
  bf16* projwt = (bf16*)(ws + 15040512);    // 2097152  [1024][1024]
  bf16* w1t    = (bf16*)(ws + 17137664);    // 5767168  [2816][1024] (rows>=2730 garbage, guarded)
  bf16* w3t    = (bf16*)(ws + 22904832);    // 5767168
  bf16* w2t    = (bf16*)(ws + 28672000);    // 5767168  [1024][2816] (cols>=2730 zero)
  float* apart = (float*)(ws + 34439168);   // 1572864 [16][4][6144]
  bf16* qb     = (bf16*)(ws + 59604992);    // 8388608 [64][1024][64]
  bf16* gbuf   = (bf16*)(ws + 59604992);    // reuse q/k/vbt: [4096][2816]
  bf16* kb     = (bf16*)(ws + 67993600);    // 8388608
  bf16* vbt    = (bf16*)(ws + 76382208);    // 8388608 [64 bh][64 d][1024 n]
  bf16* ob     = (bf16*)(ws + 84770816);    // 8388608 [4096][1024] ([B][N][H][D])

  preamble<<<13312, 256, 0, stream>>>(qkvw, projw, w1, w3, w2,
                                      qkvwt, projwt, w1t, w3t, w2t,
                                      c, adaw, apart, ropeC, ropeS);
  ada_reduce<<<96, 256, 0, stream>>>(apart, adab, mods);

  // attention branch (qkv GEMM with fused rmsnorm+rope+scatter epilogue)
  norm_mod<<<4096, 256, 0, stream>>>(x, n1w, mods, 0, 1024, xmod);
  gemm_qkv<<<768, 256, 0, stream>>>(xmod, 1024, qkvwt, 1024, ropeC, ropeS, qnw, knw,
                                    qb, kb, vbt);
  attn_fwd<<<512, 512, 0, stream>>>(qb, kb, vbt, ob);
  gemm_p<1><<<512, 256, 0, stream>>>(ob, 1024, projwt, 1024, 1024, 1024,
                                     outp, x, mods + 2048, projb);

  // MLP branch (w1+w3 fused; h1 buffer eliminated)
  norm_mod<<<4096, 256, 0, stream>>>(outp, n2w, mods, 3072, 4096, xmod);
  gemm_dual<<<704, 256, 0, stream>>>(xmod, 1024, w1t, w3t, 1024, 1024, 2730, 2816,
                                     gbuf);
  gemm_p<4><<<512, 256, 0, stream>>>(gbuf, 2816, w2t, 2816, 2816, 1024,
                                     outp, outp, mods + 5120, nullptr);
}

// Round 19
// 231.715 us; speedup vs baseline: 1.0420x; 1.0420x over previous
//
#include <hip/hip_runtime.h>
#include <hip/hip_bf16.h>
#include <stdint.h>

using bf16 = __hip_bfloat16;
using bf16x8 = __attribute__((ext_vector_type(8))) short;
using f32x4  = __attribute__((ext_vector_type(4))) float;
using short4v = __attribute__((ext_vector_type(4))) short;

#define EPSF 1e-6f
#define LOG2E 1.44269504088896f

__device__ __forceinline__ unsigned short f2bu(float x) {
  union { bf16 h; unsigned short u; } cvt;
  cvt.h = __float2bfloat16(x);
  return cvt.u;
}

typedef __attribute__((address_space(3))) void as3_void;
typedef const __attribute__((address_space(1))) void as1_void;

__device__ __forceinline__ void gload_lds16(const void* g, void* l) {
  as1_void* gp = (as1_void*)(uintptr_t)g;
  as3_void* lp = (as3_void*)(uint32_t)(uintptr_t)l;  // generic LDS ptr low 32 bits = LDS offset
  __builtin_amdgcn_global_load_lds(gp, lp, 16, 0, 0);
}

// ======== preamble: rope tables + ada stage-1 + all 5 weight transposes, one launch ====
__global__ void __launch_bounds__(256) preamble(const float* __restrict__ qkvw,
                                                const float* __restrict__ projw,
                                                const float* __restrict__ w1,
                                                const float* __restrict__ w3,
                                                const float* __restrict__ w2,
                                                bf16* __restrict__ qkvwt,
                                                bf16* __restrict__ projwt,
                                                bf16* __restrict__ w1t,
                                                bf16* __restrict__ w3t,
                                                bf16* __restrict__ w2t,
                                                const float* __restrict__ cc,
                                                const float* __restrict__ adaw,
                                                float* __restrict__ part,
                                                float* __restrict__ cosT,
                                                float* __restrict__ sinT) {
  __shared__ float tile[32][33];
  __shared__ float sc[256];
  __shared__ float red[1024];
  int id = blockIdx.x;
  const int t = threadIdx.x;
  if (id < 12416) {
    const float* src; bf16* dst; int R, Cc, ldd, nbx;
    if (id < 3072)      { src = qkvw;  dst = qkvwt;  R = 1024; Cc = 3072; ldd = 1024; nbx = 96; }
    else if ((id -= 3072) < 1024) { src = projw; dst = projwt; R = 1024; Cc = 1024; ldd = 1024; nbx = 32; }
    else if ((id -= 1024) < 2752) { src = w1;    dst = w1t;    R = 1024; Cc = 2730; ldd = 1024; nbx = 86; }
    else if ((id -= 2752) < 2752) { src = w3;    dst = w3t;    R = 1024; Cc = 2730; ldd = 1024; nbx = 86; }
    else                { id -= 2752; src = w2;    dst = w2t;    R = 2730; Cc = 1024; ldd = 2816; nbx = 32; }
    const int bx = id % nbx, by = id / nbx;
    const int tx = t & 31, ty = t >> 5;
    const int ct = bx * 32, rt = by * 32;
#pragma unroll
    for (int kk = 0; kk < 4; ++kk) {
      const int r = rt + ty + kk * 8;
      float v = 0.f;
      if (r < R && (ct + tx) < Cc) v = src[(size_t)r * Cc + ct + tx];
      tile[ty + kk * 8][tx] = v;
    }
    __syncthreads();
#pragma unroll
    for (int kk = 0; kk < 4; ++kk) {
      const int c = ct + ty + kk * 8;
      const int r = rt + tx;
      if (c < Cc && r < ldd) dst[(size_t)c * ldd + r] = __float2bfloat16(tile[tx][ty + kk * 8]);
    }
  } else if ((id -= 12416) < 768) {
    const int cb = id % 48, ks = id / 48;
    const int k0 = ks * 64;
    {
      const int b = t >> 6, kk = t & 63;
      const float v = cc[b * 1024 + k0 + kk];
      sc[t] = v / (1.f + __expf(-v));
    }
    __syncthreads();
    const int colL = t & 127, kh = t >> 7;
    const int col = cb * 128 + colL;
    float a0 = 0.f, a1 = 0.f, a2 = 0.f, a3 = 0.f;
    const float* ap = adaw + (size_t)(k0 + kh * 32) * 6144 + col;
#pragma unroll
    for (int k = 0; k < 32; ++k) {
      const float awv = ap[(size_t)k * 6144];
      const int kk = kh * 32 + k;
      a0 += sc[kk] * awv; a1 += sc[64 + kk] * awv;
      a2 += sc[128 + kk] * awv; a3 += sc[192 + kk] * awv;
    }
    red[kh * 512 + 0 * 128 + colL] = a0;
    red[kh * 512 + 1 * 128 + colL] = a1;
    red[kh * 512 + 2 * 128 + colL] = a2;
    red[kh * 512 + 3 * 128 + colL] = a3;
    __syncthreads();
    if (kh == 0) {
#pragma unroll
      for (int b = 0; b < 4; ++b) {
        const float s = red[b * 128 + colL] + red[512 + b * 128 + colL];
        part[(size_t)(ks * 4 + b) * 6144 + col] = s;
      }
    }
  } else {
    id -= 768;
    const int i = id * 256 + t;
    const int n = i >> 5, fi = i & 31;
    const float invf = powf(10000.f, -(float)fi * (1.f / 32.f));
    const float ang = (float)n * invf;
    cosT[i] = cosf(ang);
    sinT[i] = sinf(ang);
  }
}

// ---------------- ada stage 2: mods[b][col] = sum_ks partial + bias ----------------
__global__ void __launch_bounds__(256) ada_reduce(const float* __restrict__ part,
                                                  const float* __restrict__ adab,
                                                  float* __restrict__ mods) {
  const int i = blockIdx.x * 256 + threadIdx.x;   // 24576 = 4*6144
  const int b = i / 6144, col = i % 6144;
  float s = adab[col];
#pragma unroll
  for (int ks = 0; ks < 16; ++ks) s += part[(size_t)(ks * 4 + b) * 6144 + col];
  mods[b * 6144 + col] = s;
}

// ---------------- y = rmsnorm(x,w)*(1+sc)+sh  -> bf16 ----------------
__global__ void __launch_bounds__(256) norm_mod(const float* __restrict__ X,
                                                const float* __restrict__ wgt,
                                                const float* __restrict__ mods,
                                                int sh_off, int sc_off,
                                                bf16* __restrict__ Y) {
  __shared__ float red[4];
  const int row = blockIdx.x, t = threadIdx.x, l = t & 63, wv = t >> 6;
  const float4 xv = ((const float4*)(X + (size_t)row * 1024))[t];
  float ss = xv.x * xv.x + xv.y * xv.y + xv.z * xv.z + xv.w * xv.w;
#pragma unroll
  for (int off = 1; off < 64; off <<= 1) ss += __shfl_xor(ss, off);
  if (l == 0) red[wv] = ss;
  __syncthreads();
  ss = (red[0] + red[1]) + (red[2] + red[3]);
  const float rs = rsqrtf(ss * (1.f / 1024.f) + EPSF);
  const int b = row >> 10;
  const float* mb = mods + b * 6144;
  const int c0 = t * 4;
  float vals[4] = {xv.x, xv.y, xv.z, xv.w};
  short4v yv;
#pragma unroll
  for (int j = 0; j < 4; j++) {
    const int cc = c0 + j;
    const float y = vals[j] * rs * wgt[cc] * (1.f + mb[sc_off + cc]) + mb[sh_off + cc];
    yv[j] = (short)f2bu(y);
  }
  *(short4v*)(Y + (size_t)row * 1024 + c0) = yv;
}

// ======== gemm_p: C = A[M,K]@Bt[N,K]^T, 128xTN tile, 4 waves, 3-stage vmcnt ring ========
// (R12's proven config: ring-3, (256,3), m-major block order, chunk-XOR swizzle.)
template <int TN, int EPI>
__global__ void __launch_bounds__(256, 3) gemm_p(const bf16* __restrict__ A, int lda,
                                                 const bf16* __restrict__ Bt, int ldb,
                                                 int K, int Nreal, int ldc,
                                                 bf16* __restrict__ outb,
                                                 float* __restrict__ outf,
                                                 const float* __restrict__ resid,
                                                 const float* __restrict__ gate,
                                                 const float* __restrict__ bias) {
  constexpr int BUFSZ = 8192 + TN * 64;
  constexpr int WN = (TN == 128) ? 2 : 1;
  constexpr int MI = (TN == 128) ? 4 : 2;
  constexpr int WTM = (TN == 128) ? 64 : 32;
  __shared__ char smB[3 * BUFSZ];
  const int t = threadIdx.x, l = t & 63, w = t >> 6;
  const int g = l >> 4, cl = l & 15;
  const int cpx = gridDim.x >> 3;
  const int wg = blockIdx.x;
  const int swz0 = (wg & 7) * cpx + (wg >> 3);
  const int m0 = (swz0 & 31) * 128, n0 = (swz0 >> 5) * TN;   // m-major (M=4096 fixed)
  const int wm = w / WN, wn = w % WN;
  f32x4 acc[MI][4] = {};
  const int NK = K >> 5;
  const int srow = t >> 2;
  const int scol = (((t & 3) ^ ((t >> 3) & 3))) * 8;   // pre-swizzled source chunk
  const int rsw = (cl >> 1) & 3;                        // read-side chunk XOR

  auto stage = [&](int kt, int buf) {
    char* dst = smB + buf * BUFSZ;
    const int kk = kt * 32 + scol;
    gload_lds16(A + (size_t)(m0 + srow) * lda + kk,      dst + t * 16);
    gload_lds16(A + (size_t)(m0 + 64 + srow) * lda + kk, dst + 4096 + t * 16);
    gload_lds16(Bt + (size_t)(n0 + srow) * ldb + kk,     dst + 8192 + t * 16);
    if constexpr (TN == 128)
      gload_lds16(Bt + (size_t)(n0 + 64 + srow) * ldb + kk, dst + 12288 + t * 16);
  };

  stage(0, 0);
  stage(1, 1);
  if constexpr (TN == 128) asm volatile("s_waitcnt vmcnt(4)" ::: "memory");
  else                     asm volatile("s_waitcnt vmcnt(3)" ::: "memory");
  __builtin_amdgcn_s_barrier();
  __builtin_amdgcn_sched_barrier(0);
  int cur = 0;
  for (int kt = 0; kt < NK; ++kt) {
    if (kt + 2 < NK) stage(kt + 2, (cur >= 1) ? cur - 1 : 2);
    const bf16* Ab = (const bf16*)(smB + cur * BUFSZ);
    const bf16* Bb = (const bf16*)(smB + cur * BUFSZ + 8192);
    bf16x8 af[MI], bfr[4];
#pragma unroll
    for (int i = 0; i < MI; i++)
      af[i] = *(const bf16x8*)&Ab[(wm * WTM + i * 16 + cl) * 32 + ((g ^ rsw) << 3)];
#pragma unroll
    for (int i = 0; i < 4; i++)
      bfr[i] = *(const bf16x8*)&Bb[(wn * 64 + i * 16 + cl) * 32 + ((g ^ rsw) << 3)];
    __builtin_amdgcn_s_setprio(1);
#pragma unroll
    for (int mi = 0; mi < MI; mi++)
#pragma unroll
      for (int ni = 0; ni < 4; ni++)
        acc[mi][ni] = __builtin_amdgcn_mfma_f32_16x16x32_bf16(af[mi], bfr[ni], acc[mi][ni], 0, 0, 0);
    __builtin_amdgcn_s_setprio(0);
    if (kt + 2 < NK) {
      if constexpr (TN == 128) asm volatile("s_waitcnt vmcnt(4)" ::: "memory");
      else                     asm volatile("s_waitcnt vmcnt(3)" ::: "memory");
    } else {
      asm volatile("s_waitcnt vmcnt(0)" ::: "memory");
    }
    __builtin_amdgcn_s_barrier();
    __builtin_amdgcn_sched_barrier(0);
    cur = (cur + 1 == 3) ? 0 : cur + 1;
  }
#pragma unroll
  for (int mi = 0; mi < MI; mi++) {
#pragma unroll
    for (int ni = 0; ni < 4; ni++) {
      const int c = n0 + wn * 64 + ni * 16 + cl;
#pragma unroll
      for (int j = 0; j < 4; j++) {
        const int r = m0 + wm * WTM + mi * 16 + g * 4 + j;
        const float v = acc[mi][ni][j];
        if constexpr (EPI == 0) {
          if (c < Nreal) outb[(size_t)r * ldc + c] = __float2bfloat16(v);
        } else if constexpr (EPI == 1) {
          const int b = r >> 10;
          outf[(size_t)r * ldc + c] = resid[(size_t)r * ldc + c] + gate[b * 6144 + c] * (v + bias[c]);
        } else if constexpr (EPI == 4) {
          const int b = r >> 10;
          outf[(size_t)r * ldc + c] = resid[(size_t)r * ldc + c] + gate[b * 6144 + c] * v;
        }
      }
    }
  }
}

// ======== gemm_qkv: qkv GEMM with FUSED per-head rmsnorm + RoPE + scatter epilogue ======
// Q additionally scaled by 0.125*log2(e): attention softmax then runs in exp2 domain.
__global__ void __launch_bounds__(256, 3) gemm_qkv(const bf16* __restrict__ A, int lda,
                                                   const bf16* __restrict__ Bt, int ldb,
                                                   const float* __restrict__ cosT,
                                                   const float* __restrict__ sinT,
                                                   const float* __restrict__ qnw,
                                                   const float* __restrict__ knw,
                                                   bf16* __restrict__ Qo,
                                                   bf16* __restrict__ Ko,
                                                   bf16* __restrict__ vbt) {
  constexpr int BUFSZ = 16384;
  __shared__ char smB[3 * BUFSZ];
  const int t = threadIdx.x, l = t & 63, w = t >> 6;
  const int g = l >> 4, cl = l & 15;
  const int cpx = gridDim.x >> 3;
  const int wg = blockIdx.x;
  const int swz0 = (wg & 7) * cpx + (wg >> 3);
  const int m0 = (swz0 & 31) * 128, n0 = (swz0 >> 5) * 128;
  const int wm = w >> 1, wn = w & 1;
  f32x4 acc[4][4] = {};
  const int srow = t >> 2;
  const int scol = (((t & 3) ^ ((t >> 3) & 3))) * 8;
  const int rsw = (cl >> 1) & 3;

  auto stage = [&](int kt, int buf) {
    char* dst = smB + buf * BUFSZ;
    const int kk = kt * 32 + scol;
    gload_lds16(A + (size_t)(m0 + srow) * lda + kk,       dst + t * 16);
    gload_lds16(A + (size_t)(m0 + 64 + srow) * lda + kk,  dst + 4096 + t * 16);
    gload_lds16(Bt + (size_t)(n0 + srow) * ldb + kk,      dst + 8192 + t * 16);
    gload_lds16(Bt + (size_t)(n0 + 64 + srow) * ldb + kk, dst + 12288 + t * 16);
  };

  stage(0, 0);
  stage(1, 1);
  asm volatile("s_waitcnt vmcnt(4)" ::: "memory");
  __builtin_amdgcn_s_barrier();
  __builtin_amdgcn_sched_barrier(0);
  int cur = 0;
  for (int kt = 0; kt < 32; ++kt) {
    if (kt + 2 < 32) stage(kt + 2, (cur >= 1) ? cur - 1 : 2);
    const bf16* Ab = (const bf16*)(smB + cur * BUFSZ);
    const bf16* Bb = (const bf16*)(smB + cur * BUFSZ + 8192);
    bf16x8 af[4], bfr[4];
#pragma unroll
    for (int i = 0; i < 4; i++)
      af[i] = *(const bf16x8*)&Ab[(wm * 64 + i * 16 + cl) * 32 + ((g ^ rsw) << 3)];
#pragma unroll
    for (int i = 0; i < 4; i++)
      bfr[i] = *(const bf16x8*)&Bb[(wn * 64 + i * 16 + cl) * 32 + ((g ^ rsw) << 3)];
    __builtin_amdgcn_s_setprio(1);
#pragma unroll
    for (int mi = 0; mi < 4; mi++)
#pragma unroll
      for (int ni = 0; ni < 4; ni++)
        acc[mi][ni] = __builtin_amdgcn_mfma_f32_16x16x32_bf16(af[mi], bfr[ni], acc[mi][ni], 0, 0, 0);
    __builtin_amdgcn_s_setprio(0);
    if (kt + 2 < 32) asm volatile("s_waitcnt vmcnt(4)" ::: "memory");
    else             asm volatile("s_waitcnt vmcnt(0)" ::: "memory");
    __builtin_amdgcn_s_barrier();
    __builtin_amdgcn_sched_barrier(0);
    cur = (cur + 1 == 3) ? 0 : cur + 1;
  }

  // ---- stage rope tables for this token block into LDS (smB free after final barrier) --
  float* cosS = (float*)smB;            // [128][32]
  float* sinS = (float*)(smB + 16384);  // [128][32]
  const int nb0 = m0 & 1023;
  for (int i = t; i < 4096; i += 256) {
    cosS[i] = cosT[(nb0 + (i >> 5)) * 32 + (i & 31)];
    sinS[i] = sinT[(nb0 + (i >> 5)) * 32 + (i & 31)];
  }
  __syncthreads();

  const int hb = n0 + wn * 64;            // this wave's 64-col head chunk
  const int type = hb >> 10;              // 0 Q, 1 K, 2 V
  const int h = (hb & 1023) >> 6;
  const int b = m0 >> 10;
  const int bh = b * 16 + h;

  if (type == 2) {
    // V: straight copy to vbt[bh][d][n]
#pragma unroll
    for (int mi = 0; mi < 4; mi++) {
      const int r0 = m0 + wm * 64 + mi * 16 + g * 4;
      const int nn0 = r0 & 1023;
#pragma unroll
      for (int ni = 0; ni < 4; ni++) {
        const int d = ni * 16 + cl;
        short4v pv;
#pragma unroll
        for (int j = 0; j < 4; j++) pv[j] = (short)f2bu(acc[mi][ni][j]);
        *(short4v*)(vbt + (size_t)bh * 65536 + (size_t)d * 1024 + nn0) = pv;
      }
    }
  } else {
    bf16* dst = (type == 0) ? Qo : Ko;
    const float* nwp = (type == 0) ? qnw : knw;
    const float scale = (type == 0) ? 0.125f * LOG2E : 1.f;
    float wv[4];
#pragma unroll
    for (int ni = 0; ni < 4; ni++) wv[ni] = nwp[ni * 16 + cl];
#pragma unroll
    for (int mi = 0; mi < 4; mi++) {
#pragma unroll
      for (int j = 0; j < 4; j++) {
        float ssq = 0.f;
#pragma unroll
        for (int ni = 0; ni < 4; ni++) ssq += acc[mi][ni][j] * acc[mi][ni][j];
        ssq += __shfl_xor(ssq, 1);
        ssq += __shfl_xor(ssq, 2);
        ssq += __shfl_xor(ssq, 4);
        ssq += __shfl_xor(ssq, 8);
        const float rsn = rsqrtf(ssq * (1.f / 64.f) + EPSF);
        const int r = m0 + wm * 64 + mi * 16 + g * 4 + j;
        const int nn = r & 1023, rr = r - m0;
        float vn[4];
#pragma unroll
        for (int ni = 0; ni < 4; ni++) vn[ni] = acc[mi][ni][j] * rsn * wv[ni];
        const float cs0 = cosS[rr * 32 + cl],      sn0 = sinS[rr * 32 + cl];
        const float cs1 = cosS[rr * 32 + 16 + cl], sn1 = sinS[rr * 32 + 16 + cl];
        const float o0 = (vn[0] * cs0 - vn[2] * sn0) * scale;
        const float o1 = (vn[1] * cs1 - vn[3] * sn1) * scale;
        const float o2 = (vn[2] * cs0 + vn[0] * sn0) * scale;
        const float o3 = (vn[3] * cs1 + vn[1] * sn1) * scale;
        const size_t base = ((size_t)bh * 1024 + nn) * 64;
        dst[base + cl] = __float2bfloat16(o0);
        dst[base + 16 + cl] = __float2bfloat16(o1);
        dst[base + 32 + cl] = __float2bfloat16(o2);
        dst[base + 48 + cl] = __float2bfloat16(o3);
      }
    }
  }
}

// ======== gemm_dual: fused h = silu(A@W1^T)*(A@W3^T), 128x128, dual accumulators =======
// RING-2 at (256,2) (R14 proven): 48KB LDS, VGPR ~100 no spill. m-major block order.
__global__ void __launch_bounds__(256, 2) gemm_dual(const bf16* __restrict__ A, int lda,
                                                    const bf16* __restrict__ B1t,
                                                    const bf16* __restrict__ B3t, int ldb,
                                                    int K, int Nreal, int ldc,
                                                    bf16* __restrict__ outb) {
  constexpr int BUFSZ = 24576;
  __shared__ char smB[2 * BUFSZ];
  const int t = threadIdx.x, l = t & 63, w = t >> 6;
  const int g = l >> 4, cl = l & 15;
  const int cpx = gridDim.x >> 3;
  const int wg = blockIdx.x;
  const int swz0 = (wg & 7) * cpx + (wg >> 3);
  const int m0 = (swz0 & 31) * 128, n0 = (swz0 >> 5) * 128;   // m-major (M=4096 fixed)
  const int wm = w >> 1, wn = w & 1;
  f32x4 acc1[4][4] = {}, acc3[4][4] = {};
  const int NK = K >> 5;
  const int srow = t >> 2;
  const int scol = (((t & 3) ^ ((t >> 3) & 3))) * 8;
  const int rsw = (cl >> 1) & 3;

  auto stage = [&](int kt, int buf) {
    char* dst = smB + buf * BUFSZ;
    const int kk = kt * 32 + scol;
    gload_lds16(A   + (size_t)(m0 + srow) * lda + kk,      dst + t * 16);
    gload_lds16(A   + (size_t)(m0 + 64 + srow) * lda + kk, dst + 4096 + t * 16);
    gload_lds16(B1t + (size_t)(n0 + srow) * ldb + kk,      dst + 8192 + t * 16);
    gload_lds16(B1t + (size_t)(n0 + 64 + srow) * ldb + kk, dst + 12288 + t * 16);
    gload_lds16(B3t + (size_t)(n0 + srow) * ldb + kk,      dst + 16384 + t * 16);
    gload_lds16(B3t + (size_t)(n0 + 64 + srow) * ldb + kk, dst + 20480 + t * 16);
  };

  stage(0, 0);
  for (int kt = 0; kt < NK; ++kt) {
    if (kt + 1 < NK) {
      stage(kt + 1, (kt + 1) & 1);
      asm volatile("s_waitcnt vmcnt(6)" ::: "memory");
    } else {
      asm volatile("s_waitcnt vmcnt(0)" ::: "memory");
    }
    __builtin_amdgcn_s_barrier();
    __builtin_amdgcn_sched_barrier(0);
    const bf16* Ab  = (const bf16*)(smB + (kt & 1) * BUFSZ);
    const bf16* B1b = (const bf16*)(smB + (kt & 1) * BUFSZ + 8192);
    const bf16* B3b = (const bf16*)(smB + (kt & 1) * BUFSZ + 16384);
    bf16x8 af[4], b1r[4], b3r[4];
#pragma unroll
    for (int i = 0; i < 4; i++)
      af[i] = *(const bf16x8*)&Ab[(wm * 64 + i * 16 + cl) * 32 + ((g ^ rsw) << 3)];
#pragma unroll
    for (int i = 0; i < 4; i++) {
      b1r[i] = *(const bf16x8*)&B1b[(wn * 64 + i * 16 + cl) * 32 + ((g ^ rsw) << 3)];
      b3r[i] = *(const bf16x8*)&B3b[(wn * 64 + i * 16 + cl) * 32 + ((g ^ rsw) << 3)];
    }
    __builtin_amdgcn_s_setprio(1);
#pragma unroll
    for (int mi = 0; mi < 4; mi++)
#pragma unroll
      for (int ni = 0; ni < 4; ni++) {
        acc1[mi][ni] = __builtin_amdgcn_mfma_f32_16x16x32_bf16(af[mi], b1r[ni], acc1[mi][ni], 0, 0, 0);
        acc3[mi][ni] = __builtin_amdgcn_mfma_f32_16x16x32_bf16(af[mi], b3r[ni], acc3[mi][ni], 0, 0, 0);
      }
    __builtin_amdgcn_s_setprio(0);
    __builtin_amdgcn_s_barrier();
    __builtin_amdgcn_sched_barrier(0);
  }
#pragma unroll
  for (int mi = 0; mi < 4; mi++) {
#pragma unroll
    for (int ni = 0; ni < 4; ni++) {
      const int c = n0 + wn * 64 + ni * 16 + cl;
#pragma unroll
      for (int j = 0; j < 4; j++) {
        const int r = m0 + wm * 64 + mi * 16 + g * 4 + j;
        if (c < Nreal) {
          const float hv = acc1[mi][ni][j];
          const float sl = hv / (1.f + __expf(-hv));
          outb[(size_t)r * ldc + c] = __float2bfloat16(sl * acc3[mi][ni][j]);
        } else {
          outb[(size_t)r * ldc + c] = __float2bfloat16(0.f);
        }
      }
    }
  }
}

// ---------------- flash attention v7: exp2-domain softmax + defer-max (T13) ------------
__global__ void __launch_bounds__(512) attn_fwd(const bf16* __restrict__ Qb,
                                                const bf16* __restrict__ Kb,
                                                const bf16* __restrict__ Vb,
                                                bf16* __restrict__ Ob) {
  __shared__ char KsB[2 * 8192];              // [buf][64 kv][8 slots of 16B], xor-swizzled
  __shared__ char VsB[2 * 8192];              // [buf][64 d][8 kv-slots of 16B], xor-swizzled
  __shared__ unsigned short Ps[8 * 16 * 64];  // per-wave P tile [16 q][8 kv-chunks], xor-swizzled
  const int t = threadIdx.x, l = t & 63, w = t >> 6;
  const int g = l >> 4, cl = l & 15;
  const int wg = blockIdx.x;
  const int bh = wg & 63;
  const int q0 = (wg >> 6) * 128;
  const bf16* Qg = Qb + (size_t)bh * 65536;
  const bf16* Kg = Kb + (size_t)bh * 65536;
  const bf16* Vg = Vb + (size_t)bh * 65536;   // [d][n] layout
  const int qrow = q0 + w * 16 + cl;
  const bf16x8 aq0 = *(const bf16x8*)(Qg + (size_t)qrow * 64 + g * 8);
  const bf16x8 aq1 = *(const bf16x8*)(Qg + (size_t)qrow * 64 + 32 + g * 8);
  float mreg = -1e30f, lreg = 0.f;
  f32x4 o[4] = {};
  const int kr_l = t >> 3;                    // K: kv-row / V: d-row (0..63)
  const int ku = (t & 7) ^ ((t >> 3) & 7);    // source chunk for phys chunk t&7
  unsigned short* Pw = Ps + w * 1024;
  const int sxor = cl & 7;

  auto stageKV = [&](int kvt, int buf) {
    const int kv0 = kvt * 64;
    gload_lds16(Kg + (size_t)(kv0 + kr_l) * 64 + ku * 8, KsB + buf * 8192 + w * 1024);
    gload_lds16(Vg + (size_t)kr_l * 1024 + kv0 + ku * 8, VsB + buf * 8192 + w * 1024);
  };

  stageKV(0, 0);
  for (int kvt = 0; kvt < 16; ++kvt) {
    const int cb = kvt & 1;
    if (kvt + 1 < 16) {
      stageKV(kvt + 1, cb ^ 1);
      asm volatile("s_waitcnt vmcnt(2)" ::: "memory");
    } else {
      asm volatile("s_waitcnt vmcnt(0)" ::: "memory");
    }
    __builtin_amdgcn_s_barrier();
    __builtin_amdgcn_sched_barrier(0);
    const char* Kt = KsB + cb * 8192;
    const char* Vt = VsB + cb * 8192;
    f32x4 s[4] = {};
#pragma unroll
    for (int ch = 0; ch < 4; ch++) {
      const int rb = (16 * ch + cl) << 7;
      const bf16x8 bk0 = *(const bf16x8*)(Kt + rb + ((g ^ sxor) << 4));
      s[ch] = __builtin_amdgcn_mfma_f32_16x16x32_bf16(bk0, aq0, s[ch], 0, 0, 0);
      const bf16x8 bk1 = *(const bf16x8*)(Kt + rb + (((4 + g) ^ sxor) << 4));
      s[ch] = __builtin_amdgcn_mfma_f32_16x16x32_bf16(bk1, aq1, s[ch], 0, 0, 0);
    }
    float pm = fmaxf(fmaxf(fmaxf(s[0][0], s[0][1]), fmaxf(s[0][2], s[0][3])),
                     fmaxf(fmaxf(s[1][0], s[1][1]), fmaxf(s[1][2], s[1][3])));
    pm = fmaxf(pm, fmaxf(fmaxf(fmaxf(s[2][0], s[2][1]), fmaxf(s[2][2], s[2][3])),
                         fmaxf(fmaxf(s[3][0], s[3][1]), fmaxf(s[3][2], s[3][3]))));
    pm = fmaxf(pm, __shfl_xor(pm, 16));
    pm = fmaxf(pm, __shfl_xor(pm, 32));
    if (!__all(pm - mreg <= 8.f)) {           // defer-max: rescale only on real growth
      const float nm = fmaxf(mreg, pm);
      const float al = exp2f(mreg - nm);
      mreg = nm;
      lreg *= al;
#pragma unroll
      for (int dc = 0; dc < 4; dc++) {
        o[dc][0] *= al; o[dc][1] *= al; o[dc][2] *= al; o[dc][3] *= al;
      }
    }
    float rs = 0.f;
#pragma unroll
    for (int ch = 0; ch < 4; ch++) {
      const float p0 = exp2f(s[ch][0] - mreg);
      const float p1 = exp2f(s[ch][1] - mreg);
      const float p2 = exp2f(s[ch][2] - mreg);
      const float p3 = exp2f(s[ch][3] - mreg);
      rs += (p0 + p1) + (p2 + p3);
      short4v pk;
      pk[0] = (short)f2bu(p0); pk[1] = (short)f2bu(p1);
      pk[2] = (short)f2bu(p2); pk[3] = (short)f2bu(p3);
      const int phys = (2 * ch + (g >> 1)) ^ sxor;
      *(short4v*)&Pw[cl * 64 + phys * 8 + 4 * (g & 1)] = pk;
    }
    rs += __shfl_xor(rs, 16);
    rs += __shfl_xor(rs, 32);
    lreg += rs;
    const bf16x8 pa0 = *(const bf16x8*)&Pw[cl * 64 + ((g ^ sxor) << 3)];
    const bf16x8 pa1 = *(const bf16x8*)&Pw[cl * 64 + (((4 + g) ^ sxor) << 3)];
#pragma unroll
    for (int dc = 0; dc < 4; dc++) {
      const int vr = (16 * dc + cl) << 7;
      const bf16x8 bv0 = *(const bf16x8*)(Vt + vr + ((g ^ sxor) << 4));
      o[dc] = __builtin_amdgcn_mfma_f32_16x16x32_bf16(bv0, pa0, o[dc], 0, 0, 0);
      const bf16x8 bv1 = *(const bf16x8*)(Vt + vr + (((4 + g) ^ sxor) << 4));
      o[dc] = __builtin_amdgcn_mfma_f32_16x16x32_bf16(bv1, pa1, o[dc], 0, 0, 0);
    }
    __builtin_amdgcn_s_barrier();   // reads of buf cb done before next DMA into it
  }
  const int b = bh >> 4, h = bh & 15;
  const float inv = 1.f / lreg;
  const int q = q0 + w * 16 + cl;
  const size_t base = ((size_t)(b * 1024 + q) * 16 + h) * 64;
#pragma unroll
  for (int dc = 0; dc < 4; dc++) {
    short4v ov;
    ov[0] = (short)f2bu(o[dc][0] * inv);
    ov[1] = (short)f2bu(o[dc][1] * inv);
    ov[2] = (short)f2bu(o[dc][2] * inv);
    ov[3] = (short)f2bu(o[dc][3] * inv);
    *(short4v*)(Ob + base + 16 * dc + 4 * g) = ov;
  }
}

// ---------------- launch ----------------
extern "C" void kernel_launch(void* const* d_in, const int* in_sizes, int n_in,
                              void* d_out, int out_size, void* d_ws, size_t ws_size,
                              hipStream_t stream) {
  const float* x     = (const float*)d_in[0];
  const float* c     = (const float*)d_in[1];
  const float* n1w   = (const float*)d_in[2];
  const float* n2w   = (const float*)d_in[3];
  const float* qkvw  = (const float*)d_in[4];
  const float* projw = (const float*)d_in[5];
  const float* projb = (const float*)d_in[6];
  const float* qnw   = (const float*)d_in[7];
  const float* knw   = (const float*)d_in[8];
  const float* w1    = (const float*)d_in[9];
  const float* w2    = (const float*)d_in[10];
  const float* w3    = (const float*)d_in[11];
  const float* adaw  = (const float*)d_in[12];
  const float* adab  = (const float*)d_in[13];
  float* outp = (float*)d_out;
  char* ws = (char*)d_ws;
  if (ws_size < 93159424u) return;

  float* ropeC = (float*)(ws + 0);          // 131072
  float* ropeS = (float*)(ws + 131072);     // 131072
  float* mods  = (float*)(ws + 262144);     // 98304
  bf16* xmod   = (bf16*)(ws + 360448);      // 8388608
  bf16* qkvwt  = (bf16*)(ws + 8749056);     // 6291456  [3072][1024]
  bf16* projwt = (bf16*)(ws + 15040512);    // 2097152  [1024][1024]
  bf16* w1t    = (bf16*)(ws + 17137664);    // 5767168  [2816][1024] (rows>=2730 garbage, guarded)
  bf16* w3t    = (bf16*)(ws + 22904832);    // 5767168
  bf16* w2t    = (bf16*)(ws + 28672000);    // 5767168  [1024][2816] (cols>=2730 zero)
  float* apart = (float*)(ws + 34439168);   // 1572864 [16][4][6144]
  bf16* qb     = (bf16*)(ws + 59604992);    // 8388608 [64][1024][64]
  bf16* gbuf   = (bf16*)(ws + 59604992);    // reuse q/k/vbt: [4096][2816]
  bf16* kb     = (bf16*)(ws + 67993600);    // 8388608
  bf16* vbt    = (bf16*)(ws + 76382208);    // 8388608 [64 bh][64 d][1024 n]
  bf16* ob     = (bf16*)(ws + 84770816);    // 8388608 [4096][1024] ([B][N][H][D])

  preamble<<<13312, 256, 0, stream>>>(qkvw, projw, w1, w3, w2,
                                      qkvwt, projwt, w1t, w3t, w2t,
                                      c, adaw, apart, ropeC, ropeS);
  ada_reduce<<<96, 256, 0, stream>>>(apart, adab, mods);

  // attention branch (qkv GEMM with fused rmsnorm+rope+scatter epilogue)
  norm_mod<<<4096, 256, 0, stream>>>(x, n1w, mods, 0, 1024, xmod);
  gemm_qkv<<<768, 256, 0, stream>>>(xmod, 1024, qkvwt, 1024, ropeC, ropeS, qnw, knw,
                                    qb, kb, vbt);
  attn_fwd<<<512, 512, 0, stream>>>(qb, kb, vbt, ob);
  gemm_p<64, 1><<<512, 256, 0, stream>>>(ob, 1024, projwt, 1024, 1024, 1024, 1024,
                                         nullptr, outp, x, mods + 2048, projb);

  // MLP branch (w1+w3 fused; h1 buffer eliminated)
  norm_mod<<<4096, 256, 0, stream>>>(outp, n2w, mods, 3072, 4096, xmod);
  gemm_dual<<<704, 256, 0, stream>>>(xmod, 1024, w1t, w3t, 1024, 1024, 2730, 2816,
                                     gbuf);
  gemm_p<64, 4><<<512, 256, 0, stream>>>(gbuf, 2816, w2t, 2816, 2816, 1024, 1024,
                                         nullptr, outp, outp, mods + 5120, nullptr);
}